// Round 14
// baseline (136.023 us; speedup 1.0000x reference)
//
#include <hip/hip_runtime.h>

// ---------------------------------------------------------------------------
// SAGE_DGL: 2-layer GraphSAGE (mean agg) forward on MI355X.
// Round 14 (on round-13 base):
//   - agg: 2 dsts per wave interleaved (2x gather MLP), EXEC-safe shfl
//   - fill2 blocks FIRST in agg1 grid (was a bare-machine tail)
//   - GEMM1 retiled 128x64 (4x2 frags/wave)
// Pipeline: memset -> megafuse{fill1,conv x->x8+xb,conv W} -> agg1+fill2 ->
//           gemm1(+h8 epilogue) -> agg2 -> gemm2+log_softmax.
// ---------------------------------------------------------------------------

constexpr int D_IN  = 128;
constexpr int HID   = 256;
constexpr int OUT_D = 64;
constexpr int SIZE1 = 25000;
constexpr int SIZE2 = 5000;
constexpr int SEGC  = 16;                 // slots per XCD segment (1 line)
constexpr int OVFS  = 48;                 // shared overflow slots
constexpr int ROW   = 8 * SEGC + OVFS;    // 176 ints per dst row
constexpr int ECH   = 2048;               // edges per fill block (256 x 8)

using bf16x8 = __attribute__((ext_vector_type(8))) short;
using f32x4  = __attribute__((ext_vector_type(4))) float;
using f32x2  = __attribute__((ext_vector_type(2))) float;

__device__ inline unsigned short f32_to_bf16_rne(float f) {
    unsigned u = __builtin_bit_cast(unsigned, f);
    u = (u + 0x7fffu + ((u >> 16) & 1u)) >> 16;
    return (unsigned short)u;
}
__device__ inline unsigned pack_bf16(float lo, float hi) {
    return (unsigned)f32_to_bf16_rne(lo) | ((unsigned)f32_to_bf16_rne(hi) << 16);
}
// accumulate 16 fp8 values (one uint4) into a[0..15]
__device__ inline void add16(float* a, uint4 v) {
    const unsigned u[4] = {v.x, v.y, v.z, v.w};
#pragma unroll
    for (int i = 0; i < 4; ++i) {
        f32x2 f0 = __builtin_amdgcn_cvt_pk_f32_fp8(u[i], false);  // bytes 0,1
        f32x2 f1 = __builtin_amdgcn_cvt_pk_f32_fp8(u[i], true);   // bytes 2,3
        a[i * 4 + 0] += f0.x; a[i * 4 + 1] += f0.y;
        a[i * 4 + 2] += f1.x; a[i * 4 + 3] += f1.y;
    }
}

// ---------------------------------------------------------------------------
// CSR fill body (batched): 8 loads -> 8 independent atomics -> 8 stores.
// Slot segment by physical XCD id -> each 64B csr line written by one XCD.
// ---------------------------------------------------------------------------
__device__ inline void fill_body(const int* __restrict__ es,
                                 const int* __restrict__ ed, int E, int base0,
                                 int* __restrict__ cnt, int* __restrict__ ovf,
                                 int* __restrict__ csr) {
    int xcc;
    asm volatile("s_getreg_b32 %0, hwreg(HW_REG_XCC_ID)" : "=s"(xcc));
    xcc &= 7;
    constexpr int B = ECH / 256;  // 8
    int d[B], s[B], pos[B];
    bool val[B];
#pragma unroll
    for (int j = 0; j < B; ++j) {
        int e = base0 + j * 256;
        val[j] = (e < E);
        d[j] = val[j] ? ed[e] : 0;
        s[j] = val[j] ? es[e] : 0;
    }
#pragma unroll
    for (int j = 0; j < B; ++j)
        if (val[j]) pos[j] = atomicAdd(&cnt[d[j] * 8 + xcc], 1);
#pragma unroll
    for (int j = 0; j < B; ++j) {
        if (val[j]) {
            if (pos[j] < SEGC) {
                csr[(long)d[j] * ROW + xcc * SEGC + pos[j]] = s[j];
            } else {
                int po = atomicAdd(&ovf[d[j]], 1);
                if (po < OVFS) csr[(long)d[j] * ROW + 8 * SEGC + po] = s[j];
            }
        }
    }
}

// ---------------------------------------------------------------------------
// Megafuse: [0,f1) fill1 | [f1,f2) convert x -> {x8 all rows, xb first 25k} |
// [f2,..) convert weights (transposed bf16, K-concat [self||neigh]).
// ---------------------------------------------------------------------------
__global__ void megafuse(const int* __restrict__ es1, const int* __restrict__ ed1,
                         int E1, int* __restrict__ cnt1, int* __restrict__ ovf1,
                         int* __restrict__ csr1,
                         const float* __restrict__ x, unsigned* __restrict__ xbu,
                         unsigned* __restrict__ x8u, long n4,
                         const float* __restrict__ Ws1, const float* __restrict__ Wn1,
                         const float* __restrict__ Ws2, const float* __restrict__ Wn2,
                         unsigned short* __restrict__ Wt1,
                         unsigned short* __restrict__ Wt2,
                         int f1, int f2) {
    const int b = blockIdx.x;
    const int tid = threadIdx.x;
    if (b < f1) {                       // fill layer 1
        fill_body(es1, ed1, E1, b * ECH + tid, cnt1, ovf1, csr1);
    } else if (b < f2) {                // convert x
        long i0 = (long)(b - f1) * 512 + tid;
#pragma unroll
        for (int j = 0; j < 2; ++j) {
            long i = i0 + j * 256;
            if (i < n4) {
                float4 v = reinterpret_cast<const float4*>(x)[i];
                int p = __builtin_amdgcn_cvt_pk_fp8_f32(v.x, v.y, 0, false);
                p = __builtin_amdgcn_cvt_pk_fp8_f32(v.z, v.w, p, true);
                x8u[i] = (unsigned)p;
                if (i < (long)SIZE1 * (D_IN / 4)) {   // rows < 25000
                    uint2 o;
                    o.x = pack_bf16(v.x, v.y);
                    o.y = pack_bf16(v.z, v.w);
                    reinterpret_cast<uint2*>(xbu)[i] = o;
                }
            }
        }
    } else {                            // convert weights
        int i = (b - f2) * 256 + tid;
        if (i < HID * (2 * D_IN)) {     // Wt1: 256 x 256
            int n = i >> 8, k = i & 255;
            float v = (k < D_IN) ? Ws1[k * HID + n] : Wn1[(k - D_IN) * HID + n];
            Wt1[i] = f32_to_bf16_rne(v);
        } else {
            int j = i - HID * (2 * D_IN);
            if (j < OUT_D * (2 * HID)) {  // Wt2: 64 x 512
                int n = j >> 9, k = j & 511;
                float v = (k < HID) ? Ws2[k * OUT_D + n] : Wn2[(k - HID) * OUT_D + n];
                Wt2[j] = f32_to_bf16_rne(v);
            }
        }
    }
}

// ---------------------------------------------------------------------------
// Pull-mean aggregation, TWO dsts per wave (2x gather MLP), fp8 rows in,
// bf16 mean out, fp32 acc. EXEC-safe: all shfls at full wave activity;
// predication only on loads/adds. Counts for dst A in lanes 0-8, dst B in
// lanes 16-24, broadcast via shfl. Exact direct-read tail for n > 64.
// FUSE: LEADING blocks (b < fillOff) run fill_body for layer 2.
// ---------------------------------------------------------------------------
template <int GL, bool FUSE>
__global__ void agg_pull8(const uint4* __restrict__ X4,
                          const int* __restrict__ csr,
                          const int* __restrict__ cnt,
                          const int* __restrict__ ovf,
                          uint4* __restrict__ meanOut, int ndst, int fillOff,
                          const int* __restrict__ esF, const int* __restrict__ edF,
                          int EF, int* __restrict__ cntF, int* __restrict__ ovfF,
                          int* __restrict__ csrF) {
    if (FUSE && (int)blockIdx.x < fillOff) {
        fill_body(esF, edF, EF, (int)blockIdx.x * ECH + threadIdx.x,
                  cntF, ovfF, csrF);
        return;
    }
    constexpr int NG = 64 / GL;                       // groups per wave
    constexpr int NR = (64 + NG * 8 - 1) / (NG * 8);  // rounds of 8 steps
    const int db = (FUSE ? (int)blockIdx.x - fillOff : (int)blockIdx.x);
    const int wid = threadIdx.x >> 6;
    const int lane = threadIdx.x & 63;
    const int d0 = db * 8 + wid * 2;                  // wave owns d0, d0+1
    const int d1 = d0 + 1;
    if (d0 >= ndst) return;   // wave-uniform (ndst divisible by 8)

    // counts: lanes 0-7 segA, 8 ovfA, 16-23 segB, 24 ovfB
    int myc = 0;
    if (lane < 8) myc = min(cnt[d0 * 8 + lane], SEGC);
    else if (lane == 8) myc = min(ovf[d0], OVFS);
    else if (lane >= 16 && lane < 24) myc = min(cnt[d1 * 8 + (lane - 16)], SEGC);
    else if (lane == 24) myc = min(ovf[d1], OVFS);
    int cumA[10], cumB[10];
    cumA[0] = 0; cumB[0] = 0;
#pragma unroll
    for (int k = 0; k < 9; ++k) {
        cumA[k + 1] = cumA[k] + __shfl(myc, k);
        cumB[k + 1] = cumB[k] + __shfl(myc, 16 + k);
    }
    const int nA = cumA[9], nB = cumB[9];
    const long rowbA = (long)d0 * ROW, rowbB = (long)d1 * ROW;

    // lane = edge index: resolve slot once per dst, fetch src idx to register
    int slotA = lane, slotB = lane;
#pragma unroll
    for (int t = 1; t < 9; ++t) {
        if (lane >= cumA[t]) slotA = (t < 8 ? t * SEGC : 8 * SEGC) + (lane - cumA[t]);
        if (lane >= cumB[t]) slotB = (t < 8 ? t * SEGC : 8 * SEGC) + (lane - cumB[t]);
    }
    int myidxA = 0, myidxB = 0;
    if (lane < nA) myidxA = csr[rowbA + slotA];
    if (lane < nB) myidxB = csr[rowbB + slotB];

    const int g = lane / GL;       // group id
    const int c = lane % GL;       // uint4 column within the fp8 row
    const int nAm = min(nA, 64), nBm = min(nB, 64);
    const int nm = max(nAm, nBm);

    float accA[16], accB[16];
#pragma unroll
    for (int j = 0; j < 16; ++j) { accA[j] = 0.0f; accB[j] = 0.0f; }

#pragma unroll
    for (int r = 0; r < NR; ++r) {
        const int base = r * NG * 8;
        if (base < nm) {           // wave-uniform guard
            int sA[8], sB[8];
            bool aA[8], aB[8];
#pragma unroll
            for (int t = 0; t < 8; ++t) {
                const int e = base + g + NG * t;
                int xA = __shfl(myidxA, e & 63);   // full-activity shfl
                int xB = __shfl(myidxB, e & 63);
                aA[t] = (e < nAm);
                aB[t] = (e < nBm);
                sA[t] = aA[t] ? xA : 0;           // clamp: hot row-0 load
                sB[t] = aB[t] ? xB : 0;
            }
            uint4 vA[8], vB[8];
#pragma unroll
            for (int t = 0; t < 8; ++t) vA[t] = X4[(long)sA[t] * GL + c];
#pragma unroll
            for (int t = 0; t < 8; ++t) vB[t] = X4[(long)sB[t] * GL + c];
#pragma unroll
            for (int t = 0; t < 8; ++t)
                if (aA[t]) add16(accA, vA[t]);
#pragma unroll
            for (int t = 0; t < 8; ++t)
                if (aB[t]) add16(accB, vB[t]);
        }
    }
    // exact rare tails for n > 64: direct csr reads with per-edge slot chain
    for (int j2 = 64 + g; j2 < nA; j2 += NG) {
        int sl = j2;
#pragma unroll
        for (int t = 1; t < 9; ++t)
            if (j2 >= cumA[t]) sl = (t < 8 ? t * SEGC : 8 * SEGC) + (j2 - cumA[t]);
        long s0 = csr[rowbA + sl];
        uint4 v0 = X4[s0 * GL + c];
        add16(accA, v0);
    }
    for (int j2 = 64 + g; j2 < nB; j2 += NG) {
        int sl = j2;
#pragma unroll
        for (int t = 1; t < 9; ++t)
            if (j2 >= cumB[t]) sl = (t < 8 ? t * SEGC : 8 * SEGC) + (j2 - cumB[t]);
        long s0 = csr[rowbB + sl];
        uint4 v0 = X4[s0 * GL + c];
        add16(accB, v0);
    }
    // cross-group reduce (both dsts)
#pragma unroll
    for (int j = 0; j < 16; ++j) {
        if (GL == 8) { accA[j] += __shfl_xor(accA[j], 8);  accB[j] += __shfl_xor(accB[j], 8); }
        accA[j] += __shfl_xor(accA[j], 16); accB[j] += __shfl_xor(accB[j], 16);
        accA[j] += __shfl_xor(accA[j], 32); accB[j] += __shfl_xor(accB[j], 32);
    }
    const float* acc = (g == 0) ? accA : accB;
    const int dd = (g == 0) ? d0 : d1;
    const int nn = (g == 0) ? nA : nB;
    if (g < 2) {
        const float inv = 1.0f / (float)max(nn, 1);
        uint4 o0, o1;
        o0.x = pack_bf16(acc[0] * inv, acc[1] * inv);
        o0.y = pack_bf16(acc[2] * inv, acc[3] * inv);
        o0.z = pack_bf16(acc[4] * inv, acc[5] * inv);
        o0.w = pack_bf16(acc[6] * inv, acc[7] * inv);
        o1.x = pack_bf16(acc[8] * inv, acc[9] * inv);
        o1.y = pack_bf16(acc[10] * inv, acc[11] * inv);
        o1.z = pack_bf16(acc[12] * inv, acc[13] * inv);
        o1.w = pack_bf16(acc[14] * inv, acc[15] * inv);
        meanOut[(long)dd * (GL * 2) + c * 2]     = o0;  // mean row = GL*2 uint4
        meanOut[(long)dd * (GL * 2) + c * 2 + 1] = o1;
    }
}

// ---------------------------------------------------------------------------
// Fused SAGE GEMM via MFMA (bf16 in, fp32 acc), parameterized tile.
// Waves 2x2; wave tile (FM*16) x (FN*16); block tile BM=FM*32 x BN=FN*32.
// C[i][n] = act(Aself[i][:]@Wt[n][0:KPH] + Amean[i][:]@Wt[n][KPH:2KPH] + b[n])
// LDS XOR-swizzled for conflict-free ds_read_b128.
// H8: epilogue also writes fp8 copy. LSM: fused row log_softmax (BN==64).
// ---------------------------------------------------------------------------
template <int KPH, int FM, int FN, bool RELU, bool OUT_BF16, bool LSM, bool H8>
__global__ __launch_bounds__(256) void sage_gemm_mfma(
    const unsigned short* __restrict__ Aself,
    const unsigned short* __restrict__ Amean,
    const unsigned short* __restrict__ Wt,
    const float* __restrict__ bias,
    void* __restrict__ Cout, unsigned char* __restrict__ H8out, int M, int N) {
    constexpr int BM = FM * 32, BN = FN * 32;
    constexpr int ITA = (BM * KPH) / (256 * 8);
    constexpr int ITB = (BN * KPH) / (256 * 8);
    __shared__ unsigned short As[BM * KPH];
    __shared__ unsigned short Bs[BN * KPH];

    const int tid = threadIdx.x;
    const int wid = tid >> 6;
    const int lane = tid & 63;
    const int wm = wid >> 1, wn = wid & 1;
    const int rowBase = blockIdx.x * BM;
    const int colBase = blockIdx.y * BN;

    f32x4 acc[FM][FN];
#pragma unroll
    for (int a = 0; a < FM; ++a)
#pragma unroll
        for (int b = 0; b < FN; ++b)
#pragma unroll
            for (int j = 0; j < 4; ++j) acc[a][b][j] = 0.0f;

#pragma unroll
    for (int p = 0; p < 2; ++p) {
        const unsigned short* __restrict__ A = p ? Amean : Aself;
        __syncthreads();
#pragma unroll
        for (int it = 0; it < ITA; ++it) {
            int flat = (it * 256 + tid) * 8;
            int r = flat / KPH, kc = flat % KPH;
            int gr = rowBase + r;
            if (gr >= M) gr = M - 1;
            uint4 v = *reinterpret_cast<const uint4*>(&A[(long)gr * KPH + kc]);
            int idx = (r * KPH + kc) ^ ((r & 7) << 3);
            *reinterpret_cast<uint4*>(&As[idx]) = v;
        }
#pragma unroll
        for (int it = 0; it < ITB; ++it) {
            int flat = (it * 256 + tid) * 8;
            int r = flat / KPH, kc = flat % KPH;
            uint4 v = *reinterpret_cast<const uint4*>(
                &Wt[(long)(colBase + r) * (2 * KPH) + p * KPH + kc]);
            int idx = (r * KPH + kc) ^ ((r & 7) << 3);
            *reinterpret_cast<uint4*>(&Bs[idx]) = v;
        }
        __syncthreads();
#pragma unroll
        for (int kk = 0; kk < KPH / 32; ++kk) {
            bf16x8 a[FM], b[FN];
            const int kb = kk * 32 + 8 * (lane >> 4);
#pragma unroll
            for (int f = 0; f < FM; ++f) {
                int r = wm * (FM * 16) + f * 16 + (lane & 15);
                int ia = (r * KPH + kb) ^ ((r & 7) << 3);
                a[f] = *reinterpret_cast<const bf16x8*>(&As[ia]);
            }
#pragma unroll
            for (int f = 0; f < FN; ++f) {
                int rn = wn * (FN * 16) + f * 16 + (lane & 15);
                int ib = (rn * KPH + kb) ^ ((rn & 7) << 3);
                b[f] = *reinterpret_cast<const bf16x8*>(&Bs[ib]);
            }
#pragma unroll
            for (int fm = 0; fm < FM; ++fm)
#pragma unroll
                for (int fn = 0; fn < FN; ++fn)
                    acc[fm][fn] = __builtin_amdgcn_mfma_f32_16x16x32_bf16(
                        a[fm], b[fn], acc[fm][fn], 0, 0, 0);
        }
    }

    if (LSM) {
        float* sm = reinterpret_cast<float*>(As);  // BMxBN f32 <= As bytes
        __syncthreads();
#pragma unroll
        for (int fm = 0; fm < FM; ++fm)
#pragma unroll
            for (int fn = 0; fn < FN; ++fn) {
                int c = wn * (FN * 16) + fn * 16 + (lane & 15);
                float bv = bias[colBase + c];
#pragma unroll
                for (int j = 0; j < 4; ++j) {
                    int r = wm * (FM * 16) + fm * 16 + 4 * (lane >> 4) + j;
                    sm[r * BN + c] = acc[fm][fn][j] + bv;
                }
            }
        __syncthreads();
        for (int rr = 0; rr < BM / 4; ++rr) {
            int r = wid * (BM / 4) + rr;
            int gr = rowBase + r;
            if (gr >= M) continue;
            float v = sm[r * BN + lane];
            float m = v;
#pragma unroll
            for (int o = 32; o; o >>= 1) m = fmaxf(m, __shfl_xor(m, o));
            float ex = __expf(v - m);
            float s = ex;
#pragma unroll
            for (int o = 32; o; o >>= 1) s += __shfl_xor(s, o);
            ((float*)Cout)[(long)gr * N + lane] = v - m - __logf(s);
        }
    } else {
#pragma unroll
        for (int fm = 0; fm < FM; ++fm) {
#pragma unroll
            for (int fn = 0; fn < FN; ++fn) {
                int gc = colBase + wn * (FN * 16) + fn * 16 + (lane & 15);
                float bv = bias[gc];
#pragma unroll
                for (int j = 0; j < 4; ++j) {
                    int gr = rowBase + wm * (FM * 16) + fm * 16 + 4 * (lane >> 4) + j;
                    if (gr < M) {
                        float v = acc[fm][fn][j] + bv;
                        if (RELU) v = fmaxf(v, 0.0f);
                        if (OUT_BF16)
                            ((unsigned short*)Cout)[(long)gr * N + gc] =
                                f32_to_bf16_rne(v);
                        else
                            ((float*)Cout)[(long)gr * N + gc] = v;
                        if (H8) {
                            int b8 = __builtin_amdgcn_cvt_pk_fp8_f32(v, v, 0, false);
                            H8out[(long)gr * N + gc] = (unsigned char)(b8 & 0xff);
                        }
                    }
                }
            }
        }
    }
}

// ---------------------------------------------------------------------------

extern "C" void kernel_launch(void* const* d_in, const int* in_sizes, int n_in,
                              void* d_out, int out_size, void* d_ws, size_t ws_size,
                              hipStream_t stream) {
    const float* x       = (const float*)d_in[0];
    const float* Wself1  = (const float*)d_in[1];
    const float* Wneigh1 = (const float*)d_in[2];
    const float* b1      = (const float*)d_in[3];
    const float* Wself2  = (const float*)d_in[4];
    const float* Wneigh2 = (const float*)d_in[5];
    const float* b2      = (const float*)d_in[6];
    const int* es1 = (const int*)d_in[7];
    const int* ed1 = (const int*)d_in[8];
    const int* es2 = (const int*)d_in[9];
    const int* ed2 = (const int*)d_in[10];
    const int E1 = in_sizes[7];
    const int E2 = in_sizes[9];
    const long NSRC = in_sizes[0] / D_IN;  // 100000

    // ---- workspace layout (same as round 11/13) ----
    int* cnt1 = (int*)d_ws;                          // SIZE1*8
    int* ovf1 = cnt1 + (size_t)SIZE1 * 8;            // SIZE1
    int* cnt2 = ovf1 + SIZE1;                        // SIZE2*8
    int* ovf2 = cnt2 + (size_t)SIZE2 * 8;            // SIZE2
    int* csr2 = ovf2 + SIZE2;                        // SIZE2*ROW
    int* csr1 = csr2 + (size_t)SIZE2 * ROW;          // SIZE1*ROW
    const size_t zero_ints = (size_t)SIZE1 * 9 + (size_t)SIZE2 * 9;  // 270000
    const size_t int_elems = zero_ints + (size_t)SIZE2 * ROW + (size_t)SIZE1 * ROW;
    unsigned short* xb  = (unsigned short*)((int*)d_ws + int_elems);  // 25k*128
    unsigned short* mean2 = xb;                       // overlay (xb dead by agg2)
    unsigned char* x8   = (unsigned char*)(xb + (size_t)SIZE1 * D_IN);  // 100k*128
    unsigned short* Wt1 = (unsigned short*)(x8 + NSRC * D_IN);  // 256*256
    unsigned short* Wt2 = Wt1 + (size_t)HID * (2 * D_IN);       // 64*512
    unsigned short* mean1 = Wt2 + (size_t)OUT_D * (2 * HID);    // 25k*128
    unsigned char* h8   = (unsigned char*)(mean1 + (size_t)SIZE1 * D_IN);  // 25k*256
    unsigned short* h1  = (unsigned short*)csr1;     // overlay (csr1 dead by gemm1)

    hipMemsetAsync(d_ws, 0, zero_ints * sizeof(int), stream);

    // ---- megafuse: fill1 + conversions ----
    const long n4 = NSRC * D_IN / 4;                 // float4 groups in x
    const int f1 = (E1 + ECH - 1) / ECH;             // 391
    const int f2 = f1 + (int)((n4 + 511) / 512);
    const int nb_cw = (HID * (2 * D_IN) + OUT_D * (2 * HID) + 255) / 256;
    megafuse<<<f2 + nb_cw, 256, 0, stream>>>(
        es1, ed1, E1, cnt1, ovf1, csr1,
        x, (unsigned*)xb, (unsigned*)x8, n4,
        Wself1, Wneigh1, Wself2, Wneigh2, Wt1, Wt2, f1, f2);

    // ---- layer 1: fp8 pull-mean (fill2 blocks FIRST) ----
    {
        const int fillB = (E2 + ECH - 1) / ECH;      // 79
        const int aggB = SIZE1 / 8;                  // 3125 (2 dst/wave)
        agg_pull8<8, true><<<fillB + aggB, 256, 0, stream>>>(
            (const uint4*)x8, csr1, cnt1, ovf1, (uint4*)mean1, SIZE1, fillB,
            es2, ed2, E2, cnt2, ovf2, csr2);
    }
    // ---- gemm1: 128x64 tile (relu, bf16 out + fp8 h8) ----
    {
        dim3 grid((SIZE1 + 127) / 128, HID / 64);
        sage_gemm_mfma<D_IN, 4, 2, true, true, false, true>
            <<<grid, 256, 0, stream>>>(xb, mean1, Wt1, b1, h1, h8, SIZE1, HID);
    }

    // ---- layer 2: fp8 pull-mean (2 dst/wave) ----
    agg_pull8<16, false><<<SIZE2 / 8, 256, 0, stream>>>(
        (const uint4*)h8, csr2, cnt2, ovf2, (uint4*)mean2, SIZE2, 0,
        nullptr, nullptr, 0, nullptr, nullptr, nullptr);

    // ---- gemm2 + fused log_softmax (f32 out) ----
    {
        dim3 grid((SIZE2 + 63) / 64, OUT_D / 64);
        sage_gemm_mfma<HID, 2, 2, false, false, true, false>
            <<<grid, 256, 0, stream>>>(h1, mean2, Wt2, b2, d_out, nullptr,
                                       SIZE2, OUT_D);
    }
}

// Round 15
// 130.271 us; speedup vs baseline: 1.0442x; 1.0442x over previous
//
#include <hip/hip_runtime.h>

// ---------------------------------------------------------------------------
// SAGE_DGL: 2-layer GraphSAGE (mean agg) forward on MI355X.
// Round 15 = round 11 (best known, 129.9us) with dependency-driven rebalance:
//   megafuse = fill1 + x8-conv only (both feed agg1, the chain head).
//   xb-conv + Wt-conv (needed only by gemm1) move to the agg1 dispatch as
//   trailing filler blocks, hidden under the latency-bound gather.
//   (r14's 2-dst/wave agg + fill2-fronting reverted: regression.)
// Pipeline: memset -> megafuse{fill1, x->x8} ->
//           agg1{gather, +fill2, +xb-conv, +Wt-conv} ->
//           gemm1(+h8 epilogue) -> agg2 -> gemm2+log_softmax.
// ---------------------------------------------------------------------------

constexpr int D_IN  = 128;
constexpr int HID   = 256;
constexpr int OUT_D = 64;
constexpr int SIZE1 = 25000;
constexpr int SIZE2 = 5000;
constexpr int SEGC  = 16;                 // slots per XCD segment (1 line)
constexpr int OVFS  = 48;                 // shared overflow slots
constexpr int ROW   = 8 * SEGC + OVFS;    // 176 ints per dst row
constexpr int ECH   = 2048;               // edges per fill block (256 x 8)

using bf16x8 = __attribute__((ext_vector_type(8))) short;
using f32x4  = __attribute__((ext_vector_type(4))) float;
using f32x2  = __attribute__((ext_vector_type(2))) float;

__device__ inline unsigned short f32_to_bf16_rne(float f) {
    unsigned u = __builtin_bit_cast(unsigned, f);
    u = (u + 0x7fffu + ((u >> 16) & 1u)) >> 16;
    return (unsigned short)u;
}
__device__ inline unsigned pack_bf16(float lo, float hi) {
    return (unsigned)f32_to_bf16_rne(lo) | ((unsigned)f32_to_bf16_rne(hi) << 16);
}
// accumulate 16 fp8 values (one uint4) into a[0..15]
__device__ inline void add16(float* a, uint4 v) {
    const unsigned u[4] = {v.x, v.y, v.z, v.w};
#pragma unroll
    for (int i = 0; i < 4; ++i) {
        f32x2 f0 = __builtin_amdgcn_cvt_pk_f32_fp8(u[i], false);  // bytes 0,1
        f32x2 f1 = __builtin_amdgcn_cvt_pk_f32_fp8(u[i], true);   // bytes 2,3
        a[i * 4 + 0] += f0.x; a[i * 4 + 1] += f0.y;
        a[i * 4 + 2] += f1.x; a[i * 4 + 3] += f1.y;
    }
}

// ---------------------------------------------------------------------------
// CSR fill body (batched): 8 loads -> 8 independent atomics -> 8 stores.
// Slot segment by physical XCD id -> each 64B csr line written by one XCD.
// Capacity 16+48 >= max degree: exact regardless of XCC id value.
// ---------------------------------------------------------------------------
__device__ inline void fill_body(const int* __restrict__ es,
                                 const int* __restrict__ ed, int E, int base0,
                                 int* __restrict__ cnt, int* __restrict__ ovf,
                                 int* __restrict__ csr) {
    int xcc;
    asm volatile("s_getreg_b32 %0, hwreg(HW_REG_XCC_ID)" : "=s"(xcc));
    xcc &= 7;
    constexpr int B = ECH / 256;  // 8
    int d[B], s[B], pos[B];
    bool val[B];
#pragma unroll
    for (int j = 0; j < B; ++j) {
        int e = base0 + j * 256;
        val[j] = (e < E);
        d[j] = val[j] ? ed[e] : 0;
        s[j] = val[j] ? es[e] : 0;
    }
#pragma unroll
    for (int j = 0; j < B; ++j)
        if (val[j]) pos[j] = atomicAdd(&cnt[d[j] * 8 + xcc], 1);
#pragma unroll
    for (int j = 0; j < B; ++j) {
        if (val[j]) {
            if (pos[j] < SEGC) {
                csr[(long)d[j] * ROW + xcc * SEGC + pos[j]] = s[j];
            } else {
                int po = atomicAdd(&ovf[d[j]], 1);
                if (po < OVFS) csr[(long)d[j] * ROW + 8 * SEGC + po] = s[j];
            }
        }
    }
}

// ---------------------------------------------------------------------------
// Megafuse: [0,f1) fill1 | [f1,..) convert x -> x8 (fp8, all rows).
// Both outputs feed agg1 (the chain head). x8 conv doubles as co-resident
// stream work that keeps the fill waves' CUs busy (r12 lesson).
// ---------------------------------------------------------------------------
__global__ void megafuse(const int* __restrict__ es1, const int* __restrict__ ed1,
                         int E1, int* __restrict__ cnt1, int* __restrict__ ovf1,
                         int* __restrict__ csr1,
                         const float* __restrict__ x, unsigned* __restrict__ x8u,
                         long n4, int f1) {
    const int b = blockIdx.x;
    const int tid = threadIdx.x;
    if (b < f1) {                       // fill layer 1
        fill_body(es1, ed1, E1, b * ECH + tid, cnt1, ovf1, csr1);
    } else {                            // convert x -> fp8
        long i0 = (long)(b - f1) * 512 + tid;
#pragma unroll
        for (int j = 0; j < 2; ++j) {
            long i = i0 + j * 256;
            if (i < n4) {
                float4 v = reinterpret_cast<const float4*>(x)[i];
                int p = __builtin_amdgcn_cvt_pk_fp8_f32(v.x, v.y, 0, false);
                p = __builtin_amdgcn_cvt_pk_fp8_f32(v.z, v.w, p, true);
                x8u[i] = (unsigned)p;
            }
        }
    }
}

// ---------------------------------------------------------------------------
// Pull-mean aggregation from fp8 rows, bf16 mean out, fp32 accumulate.
// Wave per dst; GL lanes/group (row = GL uint4 of fp8), NG = 64/GL groups;
// NR rounds x 8 predicated steps cover n <= 64 with all shfls at full wave
// activity (EXEC-safe; r9 lesson). Exact direct-read tail for n > 64.
// FUSE trailing blocks: [aggB, +fillB) fill2 | [+NB_XB) x->xb bf16 conv |
// rest W->Wt conv — gemm1's inputs built under the gather's latency shadow.
// ---------------------------------------------------------------------------
template <int GL, bool FUSE>
__global__ void agg_pull6(const uint4* __restrict__ X4,
                          const int* __restrict__ csr,
                          const int* __restrict__ cnt,
                          const int* __restrict__ ovf,
                          uint4* __restrict__ meanOut, int ndst, int aggBlocks,
                          int fillB,
                          const int* __restrict__ esF, const int* __restrict__ edF,
                          int EF, int* __restrict__ cntF, int* __restrict__ ovfF,
                          int* __restrict__ csrF,
                          const float* __restrict__ x, unsigned* __restrict__ xbu,
                          const float* __restrict__ Ws1, const float* __restrict__ Wn1,
                          const float* __restrict__ Ws2, const float* __restrict__ Wn2,
                          unsigned short* __restrict__ Wt1,
                          unsigned short* __restrict__ Wt2) {
    if (FUSE && (int)blockIdx.x >= aggBlocks) {
        const int b = (int)blockIdx.x - aggBlocks;
        const int tid = threadIdx.x;
        constexpr int NB_XB = (SIZE1 * D_IN / 4 + 511) / 512;  // 1563
        if (b < fillB) {                 // fill layer 2
            fill_body(esF, edF, EF, b * ECH + tid, cntF, ovfF, csrF);
        } else if (b < fillB + NB_XB) {  // x -> xb (bf16), rows < 25000
            long i0 = (long)(b - fillB) * 512 + tid;
#pragma unroll
            for (int j = 0; j < 2; ++j) {
                long i = i0 + j * 256;
                if (i < (long)SIZE1 * (D_IN / 4)) {
                    float4 v = reinterpret_cast<const float4*>(x)[i];
                    uint2 o;
                    o.x = pack_bf16(v.x, v.y);
                    o.y = pack_bf16(v.z, v.w);
                    reinterpret_cast<uint2*>(xbu)[i] = o;
                }
            }
        } else {                         // weights -> Wt1/Wt2 (transposed)
            int i = (b - fillB - NB_XB) * 256 + tid;
            if (i < HID * (2 * D_IN)) {  // Wt1: 256 x 256
                int n = i >> 8, k = i & 255;
                float v = (k < D_IN) ? Ws1[k * HID + n] : Wn1[(k - D_IN) * HID + n];
                Wt1[i] = f32_to_bf16_rne(v);
            } else {
                int j = i - HID * (2 * D_IN);
                if (j < OUT_D * (2 * HID)) {  // Wt2: 64 x 512
                    int n = j >> 9, k = j & 511;
                    float v = (k < HID) ? Ws2[k * OUT_D + n]
                                        : Wn2[(k - HID) * OUT_D + n];
                    Wt2[j] = f32_to_bf16_rne(v);
                }
            }
        }
        return;
    }
    constexpr int NG = 64 / GL;                       // groups per wave
    constexpr int NR = (64 + NG * 8 - 1) / (NG * 8);  // rounds of 8 steps
    const int wid = threadIdx.x >> 6;
    const int lane = threadIdx.x & 63;
    const int d = blockIdx.x * 4 + wid;
    if (d >= ndst) return;   // wave-uniform (ndst divisible by 4)

    int myc = 0;
    if (lane < 8) myc = min(cnt[d * 8 + lane], SEGC);
    else if (lane == 8) myc = min(ovf[d], OVFS);
    int cum[10];
    cum[0] = 0;
#pragma unroll
    for (int k = 0; k < 9; ++k) cum[k + 1] = cum[k] + __shfl(myc, k);
    const int n = cum[9];
    const long rowb = (long)d * ROW;

    // lane = edge index: resolve slot once, fetch src idx into register
    int slot = lane;
#pragma unroll
    for (int t = 1; t < 9; ++t)
        if (lane >= cum[t]) slot = (t < 8 ? t * SEGC : 8 * SEGC) + (lane - cum[t]);
    int myidx = 0;
    if (lane < n) myidx = csr[rowb + slot];

    const int g = lane / GL;       // group id
    const int c = lane % GL;       // uint4 column within the fp8 row
    const int nmain = min(n, 64);

    float acc[16];
#pragma unroll
    for (int j = 0; j < 16; ++j) acc[j] = 0.0f;

#pragma unroll
    for (int r = 0; r < NR; ++r) {
        const int base = r * NG * 8;
        if (base < nmain) {        // wave-uniform guard
            int s[8];
            bool act[8];
#pragma unroll
            for (int t = 0; t < 8; ++t) {
                const int e = base + g + NG * t;
                int ss = __shfl(myidx, e & 63);   // full-activity shfl
                act[t] = (e < nmain);
                s[t] = act[t] ? ss : 0;           // clamp: harmless row-0 load
            }
            uint4 v[8];
#pragma unroll
            for (int t = 0; t < 8; ++t) v[t] = X4[(long)s[t] * GL + c];
#pragma unroll
            for (int t = 0; t < 8; ++t)
                if (act[t]) add16(acc, v[t]);
        }
    }
    // exact rare tail for n > 64: direct csr reads with per-edge slot chain
    for (int j2 = 64 + g; j2 < n; j2 += NG) {
        int sl = j2;
#pragma unroll
        for (int t = 1; t < 9; ++t)
            if (j2 >= cum[t]) sl = (t < 8 ? t * SEGC : 8 * SEGC) + (j2 - cum[t]);
        long s0 = csr[rowb + sl];
        uint4 v0 = X4[s0 * GL + c];
        add16(acc, v0);
    }
    // cross-group reduce
#pragma unroll
    for (int j = 0; j < 16; ++j) {
        if (GL == 8) acc[j] += __shfl_xor(acc[j], 8);
        acc[j] += __shfl_xor(acc[j], 16);
        acc[j] += __shfl_xor(acc[j], 32);
    }
    if (g == 0) {
        const float inv = 1.0f / (float)max(n, 1);
        uint4 o0, o1;
        o0.x = pack_bf16(acc[0] * inv, acc[1] * inv);
        o0.y = pack_bf16(acc[2] * inv, acc[3] * inv);
        o0.z = pack_bf16(acc[4] * inv, acc[5] * inv);
        o0.w = pack_bf16(acc[6] * inv, acc[7] * inv);
        o1.x = pack_bf16(acc[8] * inv, acc[9] * inv);
        o1.y = pack_bf16(acc[10] * inv, acc[11] * inv);
        o1.z = pack_bf16(acc[12] * inv, acc[13] * inv);
        o1.w = pack_bf16(acc[14] * inv, acc[15] * inv);
        meanOut[(long)d * (GL * 2) + c * 2]     = o0;  // mean row = GL*2 uint4
        meanOut[(long)d * (GL * 2) + c * 2 + 1] = o1;
    }
}

// ---------------------------------------------------------------------------
// Fused SAGE GEMM via MFMA (bf16 in, fp32 acc).
// C[i][n] = act(Aself[i][:]@Wt[n][0:KPH] + Amean[i][:]@Wt[n][KPH:2KPH] + b[n])
// 64x64 tile, 4 waves (2x2), wave does 32x32 via 2x2 16x16x32 frags.
// LDS XOR-swizzled for conflict-free ds_read_b128.
// H8: epilogue also writes fp8 copy (feeds layer-2 gather).
// LSM: fuse row log_softmax (BN=64 == full row) via LDS tile + shfl.
// ---------------------------------------------------------------------------
template <int KPH, bool RELU, bool OUT_BF16, bool LSM, bool H8>
__global__ __launch_bounds__(256) void sage_gemm_mfma(
    const unsigned short* __restrict__ Aself,
    const unsigned short* __restrict__ Amean,
    const unsigned short* __restrict__ Wt,
    const float* __restrict__ bias,
    void* __restrict__ Cout, unsigned char* __restrict__ H8out, int M, int N) {
    constexpr int BM = 64, BN = 64;
    constexpr int ITERS = (BM * KPH) / (256 * 8);
    __shared__ unsigned short As[BM * KPH];
    __shared__ unsigned short Bs[BN * KPH];

    const int tid = threadIdx.x;
    const int wid = tid >> 6;
    const int lane = tid & 63;
    const int wm = wid >> 1, wn = wid & 1;
    const int rowBase = blockIdx.x * BM;
    const int colBase = blockIdx.y * BN;

    f32x4 acc[2][2];
#pragma unroll
    for (int a = 0; a < 2; ++a)
#pragma unroll
        for (int b = 0; b < 2; ++b)
#pragma unroll
            for (int j = 0; j < 4; ++j) acc[a][b][j] = 0.0f;

#pragma unroll
    for (int p = 0; p < 2; ++p) {
        const unsigned short* __restrict__ A = p ? Amean : Aself;
        __syncthreads();
#pragma unroll
        for (int it = 0; it < ITERS; ++it) {
            int flat = (it * 256 + tid) * 8;
            int r = flat / KPH, kc = flat % KPH;
            int gr = rowBase + r;
            if (gr >= M) gr = M - 1;
            uint4 v = *reinterpret_cast<const uint4*>(&A[(long)gr * KPH + kc]);
            int idx = (r * KPH + kc) ^ ((r & 7) << 3);
            *reinterpret_cast<uint4*>(&As[idx]) = v;
        }
#pragma unroll
        for (int it = 0; it < ITERS; ++it) {
            int flat = (it * 256 + tid) * 8;
            int r = flat / KPH, kc = flat % KPH;
            uint4 v = *reinterpret_cast<const uint4*>(
                &Wt[(long)(colBase + r) * (2 * KPH) + p * KPH + kc]);
            int idx = (r * KPH + kc) ^ ((r & 7) << 3);
            *reinterpret_cast<uint4*>(&Bs[idx]) = v;
        }
        __syncthreads();
#pragma unroll
        for (int kk = 0; kk < KPH / 32; ++kk) {
            bf16x8 a[2], b[2];
            const int kb = kk * 32 + 8 * (lane >> 4);
#pragma unroll
            for (int f = 0; f < 2; ++f) {
                int r = wm * 32 + f * 16 + (lane & 15);
                int ia = (r * KPH + kb) ^ ((r & 7) << 3);
                a[f] = *reinterpret_cast<const bf16x8*>(&As[ia]);
                int rn = wn * 32 + f * 16 + (lane & 15);
                int ib = (rn * KPH + kb) ^ ((rn & 7) << 3);
                b[f] = *reinterpret_cast<const bf16x8*>(&Bs[ib]);
            }
#pragma unroll
            for (int fm = 0; fm < 2; ++fm)
#pragma unroll
                for (int fn = 0; fn < 2; ++fn)
                    acc[fm][fn] = __builtin_amdgcn_mfma_f32_16x16x32_bf16(
                        a[fm], b[fn], acc[fm][fn], 0, 0, 0);
        }
    }

    if (LSM) {
        float* sm = reinterpret_cast<float*>(As);  // 64x64 f32 = 16KB <= As
        __syncthreads();
#pragma unroll
        for (int fm = 0; fm < 2; ++fm)
#pragma unroll
            for (int fn = 0; fn < 2; ++fn) {
                int c = wn * 32 + fn * 16 + (lane & 15);
                float bv = bias[colBase + c];
#pragma unroll
                for (int j = 0; j < 4; ++j) {
                    int r = wm * 32 + fm * 16 + 4 * (lane >> 4) + j;
                    sm[r * BN + c] = acc[fm][fn][j] + bv;
                }
            }
        __syncthreads();
        for (int rr = 0; rr < 16; ++rr) {
            int r = wid * 16 + rr;
            int gr = rowBase + r;
            if (gr >= M) continue;
            float v = sm[r * BN + lane];
            float m = v;
#pragma unroll
            for (int o = 32; o; o >>= 1) m = fmaxf(m, __shfl_xor(m, o));
            float ex = __expf(v - m);
            float s = ex;
#pragma unroll
            for (int o = 32; o; o >>= 1) s += __shfl_xor(s, o);
            ((float*)Cout)[(long)gr * N + lane] = v - m - __logf(s);
        }
    } else {
#pragma unroll
        for (int fm = 0; fm < 2; ++fm) {
#pragma unroll
            for (int fn = 0; fn < 2; ++fn) {
                int gc = colBase + wn * 32 + fn * 16 + (lane & 15);
                float bv = bias[gc];
#pragma unroll
                for (int j = 0; j < 4; ++j) {
                    int gr = rowBase + wm * 32 + fm * 16 + 4 * (lane >> 4) + j;
                    if (gr < M) {
                        float v = acc[fm][fn][j] + bv;
                        if (RELU) v = fmaxf(v, 0.0f);
                        if (OUT_BF16)
                            ((unsigned short*)Cout)[(long)gr * N + gc] =
                                f32_to_bf16_rne(v);
                        else
                            ((float*)Cout)[(long)gr * N + gc] = v;
                        if (H8) {
                            int b8 = __builtin_amdgcn_cvt_pk_fp8_f32(v, v, 0, false);
                            H8out[(long)gr * N + gc] = (unsigned char)(b8 & 0xff);
                        }
                    }
                }
            }
        }
    }
}

// ---------------------------------------------------------------------------

extern "C" void kernel_launch(void* const* d_in, const int* in_sizes, int n_in,
                              void* d_out, int out_size, void* d_ws, size_t ws_size,
                              hipStream_t stream) {
    const float* x       = (const float*)d_in[0];
    const float* Wself1  = (const float*)d_in[1];
    const float* Wneigh1 = (const float*)d_in[2];
    const float* b1      = (const float*)d_in[3];
    const float* Wself2  = (const float*)d_in[4];
    const float* Wneigh2 = (const float*)d_in[5];
    const float* b2      = (const float*)d_in[6];
    const int* es1 = (const int*)d_in[7];
    const int* ed1 = (const int*)d_in[8];
    const int* es2 = (const int*)d_in[9];
    const int* ed2 = (const int*)d_in[10];
    const int E1 = in_sizes[7];
    const int E2 = in_sizes[9];
    const long NSRC = in_sizes[0] / D_IN;  // 100000

    // ---- workspace layout (same as round 11) ----
    int* cnt1 = (int*)d_ws;                          // SIZE1*8
    int* ovf1 = cnt1 + (size_t)SIZE1 * 8;            // SIZE1
    int* cnt2 = ovf1 + SIZE1;                        // SIZE2*8
    int* ovf2 = cnt2 + (size_t)SIZE2 * 8;            // SIZE2
    int* csr2 = ovf2 + SIZE2;                        // SIZE2*ROW
    int* csr1 = csr2 + (size_t)SIZE2 * ROW;          // SIZE1*ROW
    const size_t zero_ints = (size_t)SIZE1 * 9 + (size_t)SIZE2 * 9;  // 270000
    const size_t int_elems = zero_ints + (size_t)SIZE2 * ROW + (size_t)SIZE1 * ROW;
    unsigned short* xb  = (unsigned short*)((int*)d_ws + int_elems);  // 25k*128
    unsigned short* mean2 = xb;                       // overlay (xb dead by agg2)
    unsigned char* x8   = (unsigned char*)(xb + (size_t)SIZE1 * D_IN);  // 100k*128
    unsigned short* Wt1 = (unsigned short*)(x8 + NSRC * D_IN);  // 256*256
    unsigned short* Wt2 = Wt1 + (size_t)HID * (2 * D_IN);       // 64*512
    unsigned short* mean1 = Wt2 + (size_t)OUT_D * (2 * HID);    // 25k*128
    unsigned char* h8   = (unsigned char*)(mean1 + (size_t)SIZE1 * D_IN);  // 25k*256
    unsigned short* h1  = (unsigned short*)csr1;     // overlay (csr1 dead by gemm1)

    hipMemsetAsync(d_ws, 0, zero_ints * sizeof(int), stream);

    // ---- megafuse: fill1 + x->x8 (both feed agg1) ----
    const long n4 = NSRC * D_IN / 4;                 // float4 groups in x
    const int f1 = (E1 + ECH - 1) / ECH;             // 391
    const int nb_x8 = (int)((n4 + 511) / 512);       // 6250
    megafuse<<<f1 + nb_x8, 256, 0, stream>>>(
        es1, ed1, E1, cnt1, ovf1, csr1, x, (unsigned*)x8, n4, f1);

    // ---- layer 1: fp8 pull-mean + {fill2, xb-conv, Wt-conv} filler ----
    {
        const int aggB = (SIZE1 + 3) / 4;                      // 6250
        const int fillB = (E2 + ECH - 1) / ECH;                // 79
        const int nb_xb = (SIZE1 * D_IN / 4 + 511) / 512;      // 1563
        const int nb_cw = (HID * (2 * D_IN) + OUT_D * (2 * HID) + 255) / 256;  // 384
        agg_pull6<8, true><<<aggB + fillB + nb_xb + nb_cw, 256, 0, stream>>>(
            (const uint4*)x8, csr1, cnt1, ovf1, (uint4*)mean1, SIZE1, aggB, fillB,
            es2, ed2, E2, cnt2, ovf2, csr2,
            x, (unsigned*)xb, Wself1, Wneigh1, Wself2, Wneigh2, Wt1, Wt2);
    }
    // ---- gemm1 (relu, bf16 out + fp8 h8) ----
    {
        dim3 grid((SIZE1 + 63) / 64, HID / 64);
        sage_gemm_mfma<D_IN, true, true, false, true><<<grid, 256, 0, stream>>>(
            xb, mean1, Wt1, b1, h1, h8, SIZE1, HID);
    }

    // ---- layer 2: fp8 pull-mean ----
    agg_pull6<16, false><<<(SIZE2 + 3) / 4, 256, 0, stream>>>(
        (const uint4*)h8, csr2, cnt2, ovf2, (uint4*)mean2, SIZE2, 1 << 30, 0,
        nullptr, nullptr, 0, nullptr, nullptr, nullptr,
        nullptr, nullptr, nullptr, nullptr, nullptr, nullptr, nullptr, nullptr);

    // ---- gemm2 + fused log_softmax (f32 out) ----
    {
        dim3 grid((SIZE2 + 63) / 64, OUT_D / 64);
        sage_gemm_mfma<HID, false, false, true, false><<<grid, 256, 0, stream>>>(
            h1, mean2, Wt2, b2, d_out, nullptr, SIZE2, OUT_D);
    }
}

// Round 16
// 129.919 us; speedup vs baseline: 1.0470x; 1.0027x over previous
//
#include <hip/hip_runtime.h>

// ---------------------------------------------------------------------------
// SAGE_DGL: 2-layer GraphSAGE (mean agg) forward on MI355X.
// Round 16 = round 15 + LOCAL-SCOPE cnt atomics:
//   cnt[d*8+xcc] cells are XCD-private (only waves on XCD xcc touch them),
//   so the per-edge atomicAdd needs no cross-XCD coherence. Relaxed
//   workgroup-scope atomic -> executes in the local XCD L2 instead of the
//   fabric coherence point (device-scope default). ovf stays device-scope.
// Pipeline: memset -> megafuse{fill1, x->x8} ->
//           agg1{gather, +fill2, +xb-conv, +Wt-conv} ->
//           gemm1(+h8 epilogue) -> agg2 -> gemm2+log_softmax.
// ---------------------------------------------------------------------------

constexpr int D_IN  = 128;
constexpr int HID   = 256;
constexpr int OUT_D = 64;
constexpr int SIZE1 = 25000;
constexpr int SIZE2 = 5000;
constexpr int SEGC  = 16;                 // slots per XCD segment (1 line)
constexpr int OVFS  = 48;                 // shared overflow slots
constexpr int ROW   = 8 * SEGC + OVFS;    // 176 ints per dst row
constexpr int ECH   = 2048;               // edges per fill block (256 x 8)

using bf16x8 = __attribute__((ext_vector_type(8))) short;
using f32x4  = __attribute__((ext_vector_type(4))) float;
using f32x2  = __attribute__((ext_vector_type(2))) float;

__device__ inline unsigned short f32_to_bf16_rne(float f) {
    unsigned u = __builtin_bit_cast(unsigned, f);
    u = (u + 0x7fffu + ((u >> 16) & 1u)) >> 16;
    return (unsigned short)u;
}
__device__ inline unsigned pack_bf16(float lo, float hi) {
    return (unsigned)f32_to_bf16_rne(lo) | ((unsigned)f32_to_bf16_rne(hi) << 16);
}
// accumulate 16 fp8 values (one uint4) into a[0..15]
__device__ inline void add16(float* a, uint4 v) {
    const unsigned u[4] = {v.x, v.y, v.z, v.w};
#pragma unroll
    for (int i = 0; i < 4; ++i) {
        f32x2 f0 = __builtin_amdgcn_cvt_pk_f32_fp8(u[i], false);  // bytes 0,1
        f32x2 f1 = __builtin_amdgcn_cvt_pk_f32_fp8(u[i], true);   // bytes 2,3
        a[i * 4 + 0] += f0.x; a[i * 4 + 1] += f0.y;
        a[i * 4 + 2] += f1.x; a[i * 4 + 3] += f1.y;
    }
}

// ---------------------------------------------------------------------------
// CSR fill body (batched): 8 loads -> 8 independent LOCAL-scope atomics ->
// 8 stores. cnt[d*8+xcc] is XCD-private (partitioned by physical XCC_ID),
// so the atomic executes in the local XCD L2 (no fabric round-trip).
// ovf is cross-XCD (rare) -> device-scope. Capacity 16+48 >= max degree.
// ---------------------------------------------------------------------------
__device__ inline void fill_body(const int* __restrict__ es,
                                 const int* __restrict__ ed, int E, int base0,
                                 int* __restrict__ cnt, int* __restrict__ ovf,
                                 int* __restrict__ csr) {
    int xcc;
    asm volatile("s_getreg_b32 %0, hwreg(HW_REG_XCC_ID)" : "=s"(xcc));
    xcc &= 7;
    constexpr int B = ECH / 256;  // 8
    int d[B], s[B], pos[B];
    bool val[B];
#pragma unroll
    for (int j = 0; j < B; ++j) {
        int e = base0 + j * 256;
        val[j] = (e < E);
        d[j] = val[j] ? ed[e] : 0;
        s[j] = val[j] ? es[e] : 0;
    }
#pragma unroll
    for (int j = 0; j < B; ++j)
        if (val[j])
            pos[j] = __hip_atomic_fetch_add(&cnt[d[j] * 8 + xcc], 1,
                                            __ATOMIC_RELAXED,
                                            __HIP_MEMORY_SCOPE_WORKGROUP);
#pragma unroll
    for (int j = 0; j < B; ++j) {
        if (val[j]) {
            if (pos[j] < SEGC) {
                csr[(long)d[j] * ROW + xcc * SEGC + pos[j]] = s[j];
            } else {
                int po = atomicAdd(&ovf[d[j]], 1);
                if (po < OVFS) csr[(long)d[j] * ROW + 8 * SEGC + po] = s[j];
            }
        }
    }
}

// ---------------------------------------------------------------------------
// Megafuse: [0,f1) fill1 | [f1,..) convert x -> x8 (fp8, all rows).
// Both outputs feed agg1 (the chain head). x8 conv doubles as co-resident
// stream work that keeps the fill waves' CUs busy (r12 lesson).
// ---------------------------------------------------------------------------
__global__ void megafuse(const int* __restrict__ es1, const int* __restrict__ ed1,
                         int E1, int* __restrict__ cnt1, int* __restrict__ ovf1,
                         int* __restrict__ csr1,
                         const float* __restrict__ x, unsigned* __restrict__ x8u,
                         long n4, int f1) {
    const int b = blockIdx.x;
    const int tid = threadIdx.x;
    if (b < f1) {                       // fill layer 1
        fill_body(es1, ed1, E1, b * ECH + tid, cnt1, ovf1, csr1);
    } else {                            // convert x -> fp8
        long i0 = (long)(b - f1) * 512 + tid;
#pragma unroll
        for (int j = 0; j < 2; ++j) {
            long i = i0 + j * 256;
            if (i < n4) {
                float4 v = reinterpret_cast<const float4*>(x)[i];
                int p = __builtin_amdgcn_cvt_pk_fp8_f32(v.x, v.y, 0, false);
                p = __builtin_amdgcn_cvt_pk_fp8_f32(v.z, v.w, p, true);
                x8u[i] = (unsigned)p;
            }
        }
    }
}

// ---------------------------------------------------------------------------
// Pull-mean aggregation from fp8 rows, bf16 mean out, fp32 accumulate.
// Wave per dst; GL lanes/group (row = GL uint4 of fp8), NG = 64/GL groups;
// NR rounds x 8 predicated steps cover n <= 64 with all shfls at full wave
// activity (EXEC-safe; r9 lesson). Exact direct-read tail for n > 64.
// FUSE trailing blocks: [aggB, +fillB) fill2 | [+NB_XB) x->xb bf16 conv |
// rest W->Wt conv — gemm1's inputs built under the gather's latency shadow.
// ---------------------------------------------------------------------------
template <int GL, bool FUSE>
__global__ void agg_pull6(const uint4* __restrict__ X4,
                          const int* __restrict__ csr,
                          const int* __restrict__ cnt,
                          const int* __restrict__ ovf,
                          uint4* __restrict__ meanOut, int ndst, int aggBlocks,
                          int fillB,
                          const int* __restrict__ esF, const int* __restrict__ edF,
                          int EF, int* __restrict__ cntF, int* __restrict__ ovfF,
                          int* __restrict__ csrF,
                          const float* __restrict__ x, unsigned* __restrict__ xbu,
                          const float* __restrict__ Ws1, const float* __restrict__ Wn1,
                          const float* __restrict__ Ws2, const float* __restrict__ Wn2,
                          unsigned short* __restrict__ Wt1,
                          unsigned short* __restrict__ Wt2) {
    if (FUSE && (int)blockIdx.x >= aggBlocks) {
        const int b = (int)blockIdx.x - aggBlocks;
        const int tid = threadIdx.x;
        constexpr int NB_XB = (SIZE1 * D_IN / 4 + 511) / 512;  // 1563
        if (b < fillB) {                 // fill layer 2
            fill_body(esF, edF, EF, b * ECH + tid, cntF, ovfF, csrF);
        } else if (b < fillB + NB_XB) {  // x -> xb (bf16), rows < 25000
            long i0 = (long)(b - fillB) * 512 + tid;
#pragma unroll
            for (int j = 0; j < 2; ++j) {
                long i = i0 + j * 256;
                if (i < (long)SIZE1 * (D_IN / 4)) {
                    float4 v = reinterpret_cast<const float4*>(x)[i];
                    uint2 o;
                    o.x = pack_bf16(v.x, v.y);
                    o.y = pack_bf16(v.z, v.w);
                    reinterpret_cast<uint2*>(xbu)[i] = o;
                }
            }
        } else {                         // weights -> Wt1/Wt2 (transposed)
            int i = (b - fillB - NB_XB) * 256 + tid;
            if (i < HID * (2 * D_IN)) {  // Wt1: 256 x 256
                int n = i >> 8, k = i & 255;
                float v = (k < D_IN) ? Ws1[k * HID + n] : Wn1[(k - D_IN) * HID + n];
                Wt1[i] = f32_to_bf16_rne(v);
            } else {
                int j = i - HID * (2 * D_IN);
                if (j < OUT_D * (2 * HID)) {  // Wt2: 64 x 512
                    int n = j >> 9, k = j & 511;
                    float v = (k < HID) ? Ws2[k * OUT_D + n]
                                        : Wn2[(k - HID) * OUT_D + n];
                    Wt2[j] = f32_to_bf16_rne(v);
                }
            }
        }
        return;
    }
    constexpr int NG = 64 / GL;                       // groups per wave
    constexpr int NR = (64 + NG * 8 - 1) / (NG * 8);  // rounds of 8 steps
    const int wid = threadIdx.x >> 6;
    const int lane = threadIdx.x & 63;
    const int d = blockIdx.x * 4 + wid;
    if (d >= ndst) return;   // wave-uniform (ndst divisible by 4)

    int myc = 0;
    if (lane < 8) myc = min(cnt[d * 8 + lane], SEGC);
    else if (lane == 8) myc = min(ovf[d], OVFS);
    int cum[10];
    cum[0] = 0;
#pragma unroll
    for (int k = 0; k < 9; ++k) cum[k + 1] = cum[k] + __shfl(myc, k);
    const int n = cum[9];
    const long rowb = (long)d * ROW;

    // lane = edge index: resolve slot once, fetch src idx into register
    int slot = lane;
#pragma unroll
    for (int t = 1; t < 9; ++t)
        if (lane >= cum[t]) slot = (t < 8 ? t * SEGC : 8 * SEGC) + (lane - cum[t]);
    int myidx = 0;
    if (lane < n) myidx = csr[rowb + slot];

    const int g = lane / GL;       // group id
    const int c = lane % GL;       // uint4 column within the fp8 row
    const int nmain = min(n, 64);

    float acc[16];
#pragma unroll
    for (int j = 0; j < 16; ++j) acc[j] = 0.0f;

#pragma unroll
    for (int r = 0; r < NR; ++r) {
        const int base = r * NG * 8;
        if (base < nmain) {        // wave-uniform guard
            int s[8];
            bool act[8];
#pragma unroll
            for (int t = 0; t < 8; ++t) {
                const int e = base + g + NG * t;
                int ss = __shfl(myidx, e & 63);   // full-activity shfl
                act[t] = (e < nmain);
                s[t] = act[t] ? ss : 0;           // clamp: harmless row-0 load
            }
            uint4 v[8];
#pragma unroll
            for (int t = 0; t < 8; ++t) v[t] = X4[(long)s[t] * GL + c];
#pragma unroll
            for (int t = 0; t < 8; ++t)
                if (act[t]) add16(acc, v[t]);
        }
    }
    // exact rare tail for n > 64: direct csr reads with per-edge slot chain
    for (int j2 = 64 + g; j2 < n; j2 += NG) {
        int sl = j2;
#pragma unroll
        for (int t = 1; t < 9; ++t)
            if (j2 >= cum[t]) sl = (t < 8 ? t * SEGC : 8 * SEGC) + (j2 - cum[t]);
        long s0 = csr[rowb + sl];
        uint4 v0 = X4[s0 * GL + c];
        add16(acc, v0);
    }
    // cross-group reduce
#pragma unroll
    for (int j = 0; j < 16; ++j) {
        if (GL == 8) acc[j] += __shfl_xor(acc[j], 8);
        acc[j] += __shfl_xor(acc[j], 16);
        acc[j] += __shfl_xor(acc[j], 32);
    }
    if (g == 0) {
        const float inv = 1.0f / (float)max(n, 1);
        uint4 o0, o1;
        o0.x = pack_bf16(acc[0] * inv, acc[1] * inv);
        o0.y = pack_bf16(acc[2] * inv, acc[3] * inv);
        o0.z = pack_bf16(acc[4] * inv, acc[5] * inv);
        o0.w = pack_bf16(acc[6] * inv, acc[7] * inv);
        o1.x = pack_bf16(acc[8] * inv, acc[9] * inv);
        o1.y = pack_bf16(acc[10] * inv, acc[11] * inv);
        o1.z = pack_bf16(acc[12] * inv, acc[13] * inv);
        o1.w = pack_bf16(acc[14] * inv, acc[15] * inv);
        meanOut[(long)d * (GL * 2) + c * 2]     = o0;  // mean row = GL*2 uint4
        meanOut[(long)d * (GL * 2) + c * 2 + 1] = o1;
    }
}

// ---------------------------------------------------------------------------
// Fused SAGE GEMM via MFMA (bf16 in, fp32 acc).
// C[i][n] = act(Aself[i][:]@Wt[n][0:KPH] + Amean[i][:]@Wt[n][KPH:2KPH] + b[n])
// 64x64 tile, 4 waves (2x2), wave does 32x32 via 2x2 16x16x32 frags.
// LDS XOR-swizzled for conflict-free ds_read_b128.
// H8: epilogue also writes fp8 copy (feeds layer-2 gather).
// LSM: fuse row log_softmax (BN=64 == full row) via LDS tile + shfl.
// ---------------------------------------------------------------------------
template <int KPH, bool RELU, bool OUT_BF16, bool LSM, bool H8>
__global__ __launch_bounds__(256) void sage_gemm_mfma(
    const unsigned short* __restrict__ Aself,
    const unsigned short* __restrict__ Amean,
    const unsigned short* __restrict__ Wt,
    const float* __restrict__ bias,
    void* __restrict__ Cout, unsigned char* __restrict__ H8out, int M, int N) {
    constexpr int BM = 64, BN = 64;
    constexpr int ITERS = (BM * KPH) / (256 * 8);
    __shared__ unsigned short As[BM * KPH];
    __shared__ unsigned short Bs[BN * KPH];

    const int tid = threadIdx.x;
    const int wid = tid >> 6;
    const int lane = tid & 63;
    const int wm = wid >> 1, wn = wid & 1;
    const int rowBase = blockIdx.x * BM;
    const int colBase = blockIdx.y * BN;

    f32x4 acc[2][2];
#pragma unroll
    for (int a = 0; a < 2; ++a)
#pragma unroll
        for (int b = 0; b < 2; ++b)
#pragma unroll
            for (int j = 0; j < 4; ++j) acc[a][b][j] = 0.0f;

#pragma unroll
    for (int p = 0; p < 2; ++p) {
        const unsigned short* __restrict__ A = p ? Amean : Aself;
        __syncthreads();
#pragma unroll
        for (int it = 0; it < ITERS; ++it) {
            int flat = (it * 256 + tid) * 8;
            int r = flat / KPH, kc = flat % KPH;
            int gr = rowBase + r;
            if (gr >= M) gr = M - 1;
            uint4 v = *reinterpret_cast<const uint4*>(&A[(long)gr * KPH + kc]);
            int idx = (r * KPH + kc) ^ ((r & 7) << 3);
            *reinterpret_cast<uint4*>(&As[idx]) = v;
        }
#pragma unroll
        for (int it = 0; it < ITERS; ++it) {
            int flat = (it * 256 + tid) * 8;
            int r = flat / KPH, kc = flat % KPH;
            uint4 v = *reinterpret_cast<const uint4*>(
                &Wt[(long)(colBase + r) * (2 * KPH) + p * KPH + kc]);
            int idx = (r * KPH + kc) ^ ((r & 7) << 3);
            *reinterpret_cast<uint4*>(&Bs[idx]) = v;
        }
        __syncthreads();
#pragma unroll
        for (int kk = 0; kk < KPH / 32; ++kk) {
            bf16x8 a[2], b[2];
            const int kb = kk * 32 + 8 * (lane >> 4);
#pragma unroll
            for (int f = 0; f < 2; ++f) {
                int r = wm * 32 + f * 16 + (lane & 15);
                int ia = (r * KPH + kb) ^ ((r & 7) << 3);
                a[f] = *reinterpret_cast<const bf16x8*>(&As[ia]);
                int rn = wn * 32 + f * 16 + (lane & 15);
                int ib = (rn * KPH + kb) ^ ((rn & 7) << 3);
                b[f] = *reinterpret_cast<const bf16x8*>(&Bs[ib]);
            }
#pragma unroll
            for (int fm = 0; fm < 2; ++fm)
#pragma unroll
                for (int fn = 0; fn < 2; ++fn)
                    acc[fm][fn] = __builtin_amdgcn_mfma_f32_16x16x32_bf16(
                        a[fm], b[fn], acc[fm][fn], 0, 0, 0);
        }
    }

    if (LSM) {
        float* sm = reinterpret_cast<float*>(As);  // 64x64 f32 = 16KB <= As
        __syncthreads();
#pragma unroll
        for (int fm = 0; fm < 2; ++fm)
#pragma unroll
            for (int fn = 0; fn < 2; ++fn) {
                int c = wn * 32 + fn * 16 + (lane & 15);
                float bv = bias[colBase + c];
#pragma unroll
                for (int j = 0; j < 4; ++j) {
                    int r = wm * 32 + fm * 16 + 4 * (lane >> 4) + j;
                    sm[r * BN + c] = acc[fm][fn][j] + bv;
                }
            }
        __syncthreads();
        for (int rr = 0; rr < 16; ++rr) {
            int r = wid * 16 + rr;
            int gr = rowBase + r;
            if (gr >= M) continue;
            float v = sm[r * BN + lane];
            float m = v;
#pragma unroll
            for (int o = 32; o; o >>= 1) m = fmaxf(m, __shfl_xor(m, o));
            float ex = __expf(v - m);
            float s = ex;
#pragma unroll
            for (int o = 32; o; o >>= 1) s += __shfl_xor(s, o);
            ((float*)Cout)[(long)gr * N + lane] = v - m - __logf(s);
        }
    } else {
#pragma unroll
        for (int fm = 0; fm < 2; ++fm) {
#pragma unroll
            for (int fn = 0; fn < 2; ++fn) {
                int gc = colBase + wn * 32 + fn * 16 + (lane & 15);
                float bv = bias[gc];
#pragma unroll
                for (int j = 0; j < 4; ++j) {
                    int gr = rowBase + wm * 32 + fm * 16 + 4 * (lane >> 4) + j;
                    if (gr < M) {
                        float v = acc[fm][fn][j] + bv;
                        if (RELU) v = fmaxf(v, 0.0f);
                        if (OUT_BF16)
                            ((unsigned short*)Cout)[(long)gr * N + gc] =
                                f32_to_bf16_rne(v);
                        else
                            ((float*)Cout)[(long)gr * N + gc] = v;
                        if (H8) {
                            int b8 = __builtin_amdgcn_cvt_pk_fp8_f32(v, v, 0, false);
                            H8out[(long)gr * N + gc] = (unsigned char)(b8 & 0xff);
                        }
                    }
                }
            }
        }
    }
}

// ---------------------------------------------------------------------------

extern "C" void kernel_launch(void* const* d_in, const int* in_sizes, int n_in,
                              void* d_out, int out_size, void* d_ws, size_t ws_size,
                              hipStream_t stream) {
    const float* x       = (const float*)d_in[0];
    const float* Wself1  = (const float*)d_in[1];
    const float* Wneigh1 = (const float*)d_in[2];
    const float* b1      = (const float*)d_in[3];
    const float* Wself2  = (const float*)d_in[4];
    const float* Wneigh2 = (const float*)d_in[5];
    const float* b2      = (const float*)d_in[6];
    const int* es1 = (const int*)d_in[7];
    const int* ed1 = (const int*)d_in[8];
    const int* es2 = (const int*)d_in[9];
    const int* ed2 = (const int*)d_in[10];
    const int E1 = in_sizes[7];
    const int E2 = in_sizes[9];
    const long NSRC = in_sizes[0] / D_IN;  // 100000

    // ---- workspace layout (same as round 11/15) ----
    int* cnt1 = (int*)d_ws;                          // SIZE1*8
    int* ovf1 = cnt1 + (size_t)SIZE1 * 8;            // SIZE1
    int* cnt2 = ovf1 + SIZE1;                        // SIZE2*8
    int* ovf2 = cnt2 + (size_t)SIZE2 * 8;            // SIZE2
    int* csr2 = ovf2 + SIZE2;                        // SIZE2*ROW
    int* csr1 = csr2 + (size_t)SIZE2 * ROW;          // SIZE1*ROW
    const size_t zero_ints = (size_t)SIZE1 * 9 + (size_t)SIZE2 * 9;  // 270000
    const size_t int_elems = zero_ints + (size_t)SIZE2 * ROW + (size_t)SIZE1 * ROW;
    unsigned short* xb  = (unsigned short*)((int*)d_ws + int_elems);  // 25k*128
    unsigned short* mean2 = xb;                       // overlay (xb dead by agg2)
    unsigned char* x8   = (unsigned char*)(xb + (size_t)SIZE1 * D_IN);  // 100k*128
    unsigned short* Wt1 = (unsigned short*)(x8 + NSRC * D_IN);  // 256*256
    unsigned short* Wt2 = Wt1 + (size_t)HID * (2 * D_IN);       // 64*512
    unsigned short* mean1 = Wt2 + (size_t)OUT_D * (2 * HID);    // 25k*128
    unsigned char* h8   = (unsigned char*)(mean1 + (size_t)SIZE1 * D_IN);  // 25k*256
    unsigned short* h1  = (unsigned short*)csr1;     // overlay (csr1 dead by gemm1)

    hipMemsetAsync(d_ws, 0, zero_ints * sizeof(int), stream);

    // ---- megafuse: fill1 + x->x8 (both feed agg1) ----
    const long n4 = NSRC * D_IN / 4;                 // float4 groups in x
    const int f1 = (E1 + ECH - 1) / ECH;             // 391
    const int nb_x8 = (int)((n4 + 511) / 512);       // 6250
    megafuse<<<f1 + nb_x8, 256, 0, stream>>>(
        es1, ed1, E1, cnt1, ovf1, csr1, x, (unsigned*)x8, n4, f1);

    // ---- layer 1: fp8 pull-mean + {fill2, xb-conv, Wt-conv} filler ----
    {
        const int aggB = (SIZE1 + 3) / 4;                      // 6250
        const int fillB = (E2 + ECH - 1) / ECH;                // 79
        const int nb_xb = (SIZE1 * D_IN / 4 + 511) / 512;      // 1563
        const int nb_cw = (HID * (2 * D_IN) + OUT_D * (2 * HID) + 255) / 256;  // 384
        agg_pull6<8, true><<<aggB + fillB + nb_xb + nb_cw, 256, 0, stream>>>(
            (const uint4*)x8, csr1, cnt1, ovf1, (uint4*)mean1, SIZE1, aggB, fillB,
            es2, ed2, E2, cnt2, ovf2, csr2,
            x, (unsigned*)xb, Wself1, Wneigh1, Wself2, Wneigh2, Wt1, Wt2);
    }
    // ---- gemm1 (relu, bf16 out + fp8 h8) ----
    {
        dim3 grid((SIZE1 + 63) / 64, HID / 64);
        sage_gemm_mfma<D_IN, true, true, false, true><<<grid, 256, 0, stream>>>(
            xb, mean1, Wt1, b1, h1, h8, SIZE1, HID);
    }

    // ---- layer 2: fp8 pull-mean ----
    agg_pull6<16, false><<<(SIZE2 + 3) / 4, 256, 0, stream>>>(
        (const uint4*)h8, csr2, cnt2, ovf2, (uint4*)mean2, SIZE2, 1 << 30, 0,
        nullptr, nullptr, 0, nullptr, nullptr, nullptr,
        nullptr, nullptr, nullptr, nullptr, nullptr, nullptr, nullptr, nullptr);

    // ---- gemm2 + fused log_softmax (f32 out) ----
    {
        dim3 grid((SIZE2 + 63) / 64, OUT_D / 64);
        sage_gemm_mfma<HID, false, false, true, false><<<grid, 256, 0, stream>>>(
            h1, mean2, Wt2, b2, d_out, nullptr, SIZE2, OUT_D);
    }
}